// Round 4
// baseline (25.339 us; speedup 1.0000x reference)
//
#include <hip/hip_runtime.h>

// out[b,s,d] = C[idx[b,s], d] + scale(s) * P[s, d]
// B=8, S=2048, V=50257, D=1024, fp32.
// scale(s) = (s - (S-1)/2) / std(arange(S)),  std = sqrt((S^2-1)/12)

constexpr int SEQ = 2048;
constexpr int DIM = 1024;
constexpr int ROWS = 8 * SEQ;            // 16384 output rows
constexpr int RPB  = 4;                  // rows per block (SEQ % RPB == 0 -> same b within block)
// population std of arange(2048) = sqrt((2048^2 - 1)/12)
#define POS_STD 591.2066058f
#define POS_MEAN 1023.5f

typedef float f32x4 __attribute__((ext_vector_type(4)));  // native vector: OK for nontemporal builtins

__global__ __launch_bounds__(256) void embed_add_pos_kernel(
    const int* __restrict__ idx,      // [B*S]
    const float* __restrict__ C,      // [V, D]
    const float* __restrict__ P,      // [S, D]
    float* __restrict__ out)          // [B*S, D]
{
    const int row0 = blockIdx.x * RPB;       // 4 consecutive rows per block
    const int d = threadIdx.x;               // 256 threads x float4 = 1024 floats/row

    // One 16B load grabs all 4 token ids (row0 % 4 == 0 -> aligned).
    const int4 toks = *(const int4*)(idx + row0);
    const int tok[RPB] = {toks.x, toks.y, toks.z, toks.w};

    // Issue all 8 independent loads first: 4 gathered C rows + 4 P rows.
    f32x4 c[RPB], p[RPB];
#pragma unroll
    for (int i = 0; i < RPB; ++i) {
        const int s = (row0 + i) & (SEQ - 1);
        c[i] = ((const f32x4*)(C + (size_t)tok[i] * DIM))[d];
        p[i] = ((const f32x4*)(P + (size_t)s * DIM))[d];
    }

#pragma unroll
    for (int i = 0; i < RPB; ++i) {
        const int s = (row0 + i) & (SEQ - 1);
        const float scale = ((float)s - POS_MEAN) / POS_STD;
        f32x4 r;
        r.x = fmaf(scale, p[i].x, c[i].x);
        r.y = fmaf(scale, p[i].y, c[i].y);
        r.z = fmaf(scale, p[i].z, c[i].z);
        r.w = fmaf(scale, p[i].w, c[i].w);
        // Output is write-once, never re-read: stream it past L2.
        __builtin_nontemporal_store(r, &((f32x4*)(out + (size_t)(row0 + i) * DIM))[d]);
    }
}

extern "C" void kernel_launch(void* const* d_in, const int* in_sizes, int n_in,
                              void* d_out, int out_size, void* d_ws, size_t ws_size,
                              hipStream_t stream) {
    const int*   idx = (const int*)d_in[0];     // inputs [B,S] (int32)
    const float* C   = (const float*)d_in[1];   // content_kernel [V,D]
    const float* P   = (const float*)d_in[2];   // position_kernel [S,D]
    float* out = (float*)d_out;

    embed_add_pos_kernel<<<ROWS / RPB, 256, 0, stream>>>(idx, C, P, out);
}